// Round 4
// baseline (88.733 us; speedup 1.0000x reference)
//
#include <hip/hip_runtime.h>

// PointTransformerV3 — algebraic simplification, fused single kernel, ALL FP32.
//
// Reference: attn = softmax(attn, axis=2); out = sum(attn, axis=2) * v.
// sum_j softmax_j(...) == 1 exactly, so out = v = x @ wv, then
// out = relu(v @ wo + bo). pos_enc MLP, q/k, energy, attention MLP and
// softmax all cancel out of the final value.
//
// Round-4 change: inputs are FP32 (reference dtype), not bf16. Reading fp32
// as bf16 produced NaN accumulators in rounds 0-3; fmaxf(NaN,0)=0 zeroed
// every output, reproducing the empty-stub absmax exactly.
//
// Shapes: x [768,128], wv [128,128], wo [128,128], bo [128]. fp32 in/out.

#define NPTS 768
#define DIM  128

__global__ void __launch_bounds__(DIM) ptv3_fused_f32(
    const float* __restrict__ x,
    const float* __restrict__ wv,
    const float* __restrict__ wo,
    const float* __restrict__ bo,
    float* __restrict__ out)
{
    __shared__ float xs[DIM];   // x[i,:]
    __shared__ float vs[DIM];   // v[i,:] = x[i,:] @ wv

    const int i = blockIdx.x;       // point row 0..767
    const int e = threadIdx.x;      // feature 0..127

    xs[e] = x[i * DIM + e];
    __syncthreads();

    // v[e] = sum_c x[c] * wv[c,e]   (lane e reads column e; consecutive
    // lanes hit consecutive addresses each iteration -> coalesced)
    float acc = 0.f;
#pragma unroll 8
    for (int c = 0; c < DIM; ++c) {
        acc = fmaf(xs[c], wv[c * DIM + e], acc);
    }
    vs[e] = acc;
    __syncthreads();

    // out[e] = relu(bo[e] + sum_d v[d] * wo[d,e])
    float acc2 = bo[e];
#pragma unroll 8
    for (int d = 0; d < DIM; ++d) {
        acc2 = fmaf(vs[d], wo[d * DIM + e], acc2);
    }
    out[i * DIM + e] = fmaxf(acc2, 0.f);
}

extern "C" void kernel_launch(void* const* d_in, const int* in_sizes, int n_in,
                              void* d_out, int out_size, void* d_ws, size_t ws_size,
                              hipStream_t stream)
{
    // setup_inputs() order:
    // 0:x 1:pos 2:pe_w1 3:pe_b1 4:pe_w2 5:pe_b2
    // 6:am_w1 7:am_b1 8:am_w2 9:am_b2 10:wq 11:wk 12:wv 13:wo 14:bo
    const float* x  = (const float*)d_in[0];
    const float* wv = (const float*)d_in[12];
    const float* wo = (const float*)d_in[13];
    const float* bo = (const float*)d_in[14];
    float* out = (float*)d_out;

    (void)d_ws; (void)ws_size; (void)in_sizes; (void)n_in; (void)out_size;

    ptv3_fused_f32<<<NPTS, DIM, 0, stream>>>(x, wv, wo, bo, out);
}